// Round 8
// baseline (154.555 us; speedup 1.0000x reference)
//
#include <hip/hip_runtime.h>

#define HID   384
#define K_PE  768     // 3*16*16
#define IMGST 150528  // 3*224*224 floats per image
#define NCOLS 75264   // 196*384

typedef unsigned short ushort_t;
using f32x4  = __attribute__((ext_vector_type(4))) float;
using short8 = __attribute__((ext_vector_type(8))) short;

// ---- bf16 helpers (RNE) ----------------------------------------------------
__device__ __forceinline__ unsigned bfpack(float lo, float hi) {
    union { float f; unsigned u; } a, b; a.f = lo; b.f = hi;
    unsigned ra = (a.u + 0x7fffu + ((a.u >> 16) & 1u)) >> 16;
    unsigned rb = (b.u + 0x7fffu + ((b.u >> 16) & 1u)) & 0xffff0000u;
    return ra | rb;
}

// ---------------- prep: zero scal/Lsum/Qsum + swizzle W into B-frag order ---
// Wfrag: [nt(24)][kc(24)][lane(64)][8] bf16; B-frag n = nt*16 + (lane&15),
// k = kc*32 + (lane>>4)*8 + j -> one frag load = one contiguous 1 KB segment.
// grid 148 x 256 = 37888 threads.
__global__ __launch_bounds__(256) void prep(const float* __restrict__ W,
                                            ushort_t* __restrict__ Wfrag,
                                            float* __restrict__ scal,
                                            float* __restrict__ Lsum,
                                            float* __restrict__ Qsum) {
    const int t = blockIdx.x * 256 + threadIdx.x;
    if (t < 4) scal[t] = 0.f;                  // T, S, pad, done-counter
    if (t < NCOLS / 4) {
        ((float4*)Lsum)[t] = float4{0.f, 0.f, 0.f, 0.f};
        ((float4*)Qsum)[t] = float4{0.f, 0.f, 0.f, 0.f};
    }
    if (t < 36864) {
        const int n  = t / 96;                 // 0..383
        const int ko = t % 96;                 // k-octet
        const float4 a = *(const float4*)(W + (size_t)n * K_PE + ko * 8);
        const float4 b = *(const float4*)(W + (size_t)n * K_PE + ko * 8 + 4);
        uint4 p;
        p.x = bfpack(a.x, a.y); p.y = bfpack(a.z, a.w);
        p.z = bfpack(b.x, b.y); p.w = bfpack(b.z, b.w);
        const int nt   = n >> 4;
        const int kc   = ko >> 2;
        const int lane = (ko & 3) * 16 + (n & 15);
        ((uint4*)Wfrag)[(nt * 24 + kc) * 64 + lane] = p;
    }
}

// ---------------- fused patch-embed + softmax + partial reduce --------------
// grid (196, 4): block = (position p, image-quarter ig). Block 256 = 4 waves.
// M = 16 images, N = 384 (4 n-waves x 96), K = 768 in 64-chunks, x and y
// GEMMs share B-frags. Epilogue: fused row softmax (fp32), then per-block
//   T_part = sum logp*q  -> atomic scal[0]
//   L[c],Q[c] col sums over 16 images -> atomic Lsum/Qsum[p*384+c]
__global__ __launch_bounds__(256, 4) void pe_all(
    const float* __restrict__ xin, const float* __restrict__ yin,
    const ushort_t* __restrict__ Wfrag, const float* __restrict__ bias,
    float* __restrict__ scal, float* __restrict__ Lsum,
    float* __restrict__ Qsum) {
    const int p  = blockIdx.x;
    const int ig = blockIdx.y;        // image quarter
    const int pi = p / 14;
    const int pj = p - pi * 14;

    __shared__ __align__(16) ushort_t As[2][2][16 * 64];  // [input][buf] 4 KB
    __shared__ float Smx[4][16], Ssx[4][16], Smy[4][16], Ssy[4][16];
    __shared__ float sT[4];

    const int tid  = threadIdx.x;
    const int wave = tid >> 6;
    const int lane = tid & 63;
    const int lm   = lane & 15;
    const int lq   = lane >> 4;
    const int wn   = wave * 96;

    // ---- A staging: input z = tid>>7; row sm (image), k-octet qt
    const int z  = tid >> 7;
    const int sm = (tid >> 3) & 15;
    const int qt = tid & 7;
    const float* ab = (z ? yin : xin) +
                      (size_t)(ig * 16 + sm) * IMGST + pi * 3584 + pj * 16;
    ushort_t* awp = &As[z][0][sm * 64 + ((qt ^ (sm & 7)) * 8)];

    // ---- frag read offsets (k-step invariant): A row = lm
    int ard[2];
#pragma unroll
    for (int ks = 0; ks < 2; ++ks)
        ard[ks] = lm * 64 + (((ks * 4 + lq) ^ (lm & 7)) * 8);

    const ushort_t* bbase = Wfrag + (size_t)lane * 8;

    f32x4 accx[6] = {};
    f32x4 accy[6] = {};

#define STAGE(KB, BUF)                                                       \
    {                                                                        \
        const int k0  = (KB) + qt * 8;                                       \
        const int off = (k0 >> 8) * 50176 + (((k0 >> 4) & 15) * 224) + (k0 & 15); \
        float4 f0 = *(const float4*)(ab + off);                              \
        float4 f1 = *(const float4*)(ab + off + 4);                          \
        uint4 px;                                                            \
        px.x = bfpack(f0.x, f0.y); px.y = bfpack(f0.z, f0.w);                \
        px.z = bfpack(f1.x, f1.y); px.w = bfpack(f1.z, f1.w);                \
        *(uint4*)(awp + (BUF) * 1024) = px;                                  \
    }

    STAGE(0, 0)
    __syncthreads();

    for (int kbi = 0; kbi < 12; ++kbi) {
        const int cur = kbi & 1;
        if (kbi < 11) STAGE(kbi * 64 + 64, cur ^ 1)
#pragma unroll
        for (int ks = 0; ks < 2; ++ks) {
            short8 bfr[6];
#pragma unroll
            for (int ni = 0; ni < 6; ++ni)
                bfr[ni] = *(const short8*)(bbase +
                          (size_t)(((wave * 6 + ni) * 24 + kbi * 2 + ks) * 64) * 8);
            short8 afx = *(const short8*)&As[0][cur][ard[ks]];
            short8 afy = *(const short8*)&As[1][cur][ard[ks]];
#pragma unroll
            for (int ni = 0; ni < 6; ++ni) {
                accx[ni] = __builtin_amdgcn_mfma_f32_16x16x32_bf16(
                    afx, bfr[ni], accx[ni], 0, 0, 0);
                accy[ni] = __builtin_amdgcn_mfma_f32_16x16x32_bf16(
                    afy, bfr[ni], accy[ni], 0, 0, 0);
            }
        }
        __syncthreads();
    }
#undef STAGE

    // ---- epilogue ----------------------------------------------------------
    // D frag: col = wn + ni*16 + lm; row (image in quarter) = lq*4 + r.
#pragma unroll
    for (int ni = 0; ni < 6; ++ni) {
        const float bv = bias[wn + ni * 16 + lm];
#pragma unroll
        for (int r = 0; r < 4; ++r) {
            accx[ni][r] += bv;
            accy[ni][r] += bv;
        }
    }

    // row max, butterfly within the 16-lane lm group
    float mx[4], my_[4];
#pragma unroll
    for (int r = 0; r < 4; ++r) {
        float a = accx[0][r], b = accy[0][r];
#pragma unroll
        for (int ni = 1; ni < 6; ++ni) {
            a = fmaxf(a, accx[ni][r]);
            b = fmaxf(b, accy[ni][r]);
        }
        mx[r] = a; my_[r] = b;
    }
#pragma unroll
    for (int off = 1; off < 16; off <<= 1)
#pragma unroll
        for (int r = 0; r < 4; ++r) {
            mx[r]  = fmaxf(mx[r],  __shfl_xor(mx[r],  off));
            my_[r] = fmaxf(my_[r], __shfl_xor(my_[r], off));
        }
    if (lm == 0)
#pragma unroll
        for (int r = 0; r < 4; ++r) {
            Smx[wave][lq * 4 + r] = mx[r];
            Smy[wave][lq * 4 + r] = my_[r];
        }
    __syncthreads();
#pragma unroll
    for (int r = 0; r < 4; ++r) {
        const int row = lq * 4 + r;
        mx[r]  = fmaxf(fmaxf(Smx[0][row], Smx[1][row]),
                       fmaxf(Smx[2][row], Smx[3][row]));
        my_[r] = fmaxf(fmaxf(Smy[0][row], Smy[1][row]),
                       fmaxf(Smy[2][row], Smy[3][row]));
    }

    // row sum of exp
    float sx[4], sy[4];
#pragma unroll
    for (int r = 0; r < 4; ++r) {
        float a = 0.f, b = 0.f;
#pragma unroll
        for (int ni = 0; ni < 6; ++ni) {
            a += __expf(accx[ni][r] - mx[r]);
            b += __expf(accy[ni][r] - my_[r]);
        }
        sx[r] = a; sy[r] = b;
    }
#pragma unroll
    for (int off = 1; off < 16; off <<= 1)
#pragma unroll
        for (int r = 0; r < 4; ++r) {
            sx[r] += __shfl_xor(sx[r], off);
            sy[r] += __shfl_xor(sy[r], off);
        }
    if (lm == 0)
#pragma unroll
        for (int r = 0; r < 4; ++r) {
            Ssx[wave][lq * 4 + r] = sx[r];
            Ssy[wave][lq * 4 + r] = sy[r];
        }
    __syncthreads();
#pragma unroll
    for (int r = 0; r < 4; ++r) {
        const int row = lq * 4 + r;
        const float ssx = Ssx[0][row] + Ssx[1][row] + Ssx[2][row] + Ssx[3][row];
        const float ssy = Ssy[0][row] + Ssy[1][row] + Ssy[2][row] + Ssy[3][row];
        sx[r] = mx[r] + __logf(ssx);   // logp shift
        sy[r] = 1.f / ssy;             // q scale
    }

    // T partial + col sums over this block's 16 images
    float T = 0.f;
    float cL[6], cQ[6];
#pragma unroll
    for (int ni = 0; ni < 6; ++ni) { cL[ni] = 0.f; cQ[ni] = 0.f; }
#pragma unroll
    for (int r = 0; r < 4; ++r) {
        const float sh  = sx[r];
        const float m   = my_[r];
        const float inv = sy[r];
#pragma unroll
        for (int ni = 0; ni < 6; ++ni) {
            const float lp = accx[ni][r] - sh;
            const float qv = __expf(accy[ni][r] - m) * inv;
            T += lp * qv;
            cL[ni] += lp;
            cQ[ni] += qv;
        }
    }
    // reduce col sums over the 4 lq groups (rows) -> every lane holds 16-row sum
#pragma unroll
    for (int ni = 0; ni < 6; ++ni) {
        cL[ni] += __shfl_xor(cL[ni], 16); cL[ni] += __shfl_xor(cL[ni], 32);
        cQ[ni] += __shfl_xor(cQ[ni], 16); cQ[ni] += __shfl_xor(cQ[ni], 32);
    }
    if (lq == 0)
#pragma unroll
        for (int ni = 0; ni < 6; ++ni) {
            const int col = p * HID + wn + ni * 16 + lm;
            atomicAdd(&Lsum[col], cL[ni]);
            atomicAdd(&Qsum[col], cQ[ni]);
        }
    // block-reduce T -> one atomic
#pragma unroll
    for (int off = 32; off > 0; off >>= 1) T += __shfl_xor(T, off);
    if (lane == 0) sT[wave] = T;
    __syncthreads();
    if (tid == 0)
        atomicAdd(&scal[0], sT[0] + sT[1] + sT[2] + sT[3]);
}

// ---------------- S = dot(Lsum,Qsum) + finalize -----------------------------
// grid 74 x 256; last-done block computes out = 63*T/(S-T).
__global__ __launch_bounds__(256) void final_dot(const float* __restrict__ Lsum,
                                                 const float* __restrict__ Qsum,
                                                 float* __restrict__ scal,
                                                 float* __restrict__ out) {
    const int idx = blockIdx.x * 256 + threadIdx.x;
    float s = 0.f;
    if (idx < NCOLS / 4) {
        float4 a = ((const float4*)Lsum)[idx];
        float4 b = ((const float4*)Qsum)[idx];
        s = a.x * b.x + a.y * b.y + a.z * b.z + a.w * b.w;
    }
#pragma unroll
    for (int off = 32; off > 0; off >>= 1) s += __shfl_xor(s, off);
    __shared__ float sS[4];
    __shared__ int lastflag;
    if ((threadIdx.x & 63) == 0) sS[threadIdx.x >> 6] = s;
    __syncthreads();
    if (threadIdx.x == 0) {
        atomicAdd(&scal[1], sS[0] + sS[1] + sS[2] + sS[3]);
        __threadfence();
        int old = atomicAdd((int*)&scal[3], 1);
        lastflag = (old == (int)gridDim.x - 1);
    }
    __syncthreads();
    if (lastflag && threadIdx.x == 0) {
        float S = atomicAdd(&scal[1], 0.f);   // coherent read-back
        float T = atomicAdd(&scal[0], 0.f);
        out[0] = 63.f * T / (S - T);
    }
}

extern "C" void kernel_launch(void* const* d_in, const int* in_sizes, int n_in,
                              void* d_out, int out_size, void* d_ws, size_t ws_size,
                              hipStream_t stream) {
    const float* x = (const float*)d_in[0];   // (64,3,224,224)
    const float* y = (const float*)d_in[1];   // (64,3,224,224)
    const float* W = (const float*)d_in[2];   // (384,768)
    const float* b = (const float*)d_in[3];   // (384,)
    float* out = (float*)d_out;

    float*    scal  = (float*)d_ws;                   // 16 f32: T,S,pad,cnt
    float*    Lsum  = scal + 16;                      // 75264 f32
    float*    Qsum  = Lsum + NCOLS;                   // 75264 f32
    ushort_t* Wfrag = (ushort_t*)(Qsum + NCOLS);      // 294912 bf16

    prep<<<148, 256, 0, stream>>>(W, Wfrag, scal, Lsum, Qsum);
    pe_all<<<dim3(196, 4), 256, 0, stream>>>(x, y, Wfrag, b, scal, Lsum, Qsum);
    final_dot<<<74, 256, 0, stream>>>(Lsum, Qsum, scal, out);
}